// Round 6
// baseline (153.145 us; speedup 1.0000x reference)
//
#include <hip/hip_runtime.h>
#include <cmath>

// Kalman_Smooth_Gradient: B=4096 seqs, T=128 steps, 6-state EKF + RTS + loss.
// Round 21: r20 post-mortem: tvg4 offload was net-negative vs r18 (best filt
// = 48.3us); removing VALU didn't help (stall-knee), adding traffic hurt.
// Revert filt to r18 exactly. New lever: dispatch-count. Bench overhead grew
// ~10us going 1->3 kernels; fuse the reduce INTO filt via last-block-of-
// seq-group cleanup (atomic counter, no spin): blocks f=0,1,2 of seq-group
// sg share counter[sg]; the block whose atomicAdd returns 2 reduces the
// group's aq slice (3 x 126 coalesced 512B rows) and atomicAdds out.
// Counters zeroed by ztrans block 0 (stream-ordered). Dispatches: memset,
// ztrans, filt.

namespace {

constexpr int B = 4096;
constexpr int T = 128;
constexpr int NT = B * 3;           // 12288 filter chains
constexpr int CPB = 64;             // chains (= threads) per block, one wave
constexpr int NBLK = NT / CPB;      // 192 blocks

constexpr float DTc     = 1.0f / 120.0f;
constexpr float TWO_PIc = 6.28318530717958647692f;
constexpr float PI_1_5  = 4.71238898038468985769f;
constexpr float INV_2PI = 0.15915494309189533577f;

__device__ __forceinline__ float frcp(float x) { return __builtin_amdgcn_rcpf(x); }

__device__ __forceinline__ float fast_tanh(float x) {
  float e = __expf(2.0f * x);
  return 1.0f - 2.0f * frcp(e + 1.0f);
}
__device__ __forceinline__ float sigmoidf(float x) {
  return frcp(1.0f + __expf(-x));
}

// ---------------------------------------------------------------------------
// z transpose: z[s][t][f] -> zt[f][t][s]. Block = 256 thr, tile = 64 seqs x
// 32 t x 3 f (24960 B LDS, stride-65 cols). Grid 256 blocks. Block 0 also
// zeroes the 64 seq-group counters used by filt's fused reduce.
// ---------------------------------------------------------------------------
__global__ __launch_bounds__(256) void ztrans_kernel(
    const float* __restrict__ z, float* __restrict__ zt,
    unsigned* __restrict__ cnt) {
  __shared__ float tile[96 * 65];
  const int tid = threadIdx.x;
  if (blockIdx.x == 0 && tid < 64) cnt[tid] = 0u;
  const int bs = blockIdx.x & 63;        // seq-chunk 0..63
  const int bt = blockIdx.x >> 6;        // t-chunk 0..3
  const int s0 = bs * 64, t0 = bt * 32;

  const float* __restrict__ zbase = z + (size_t)s0 * 384 + t0 * 3;
#pragma unroll
  for (int k = 0; k < 6; k++) {
    const int idx = tid + k * 256;       // 0..1535
    const int sl = idx / 24;             // seq-local 0..63
    const int c4 = idx - sl * 24;        // float4 col 0..23
    const float4 v4 = *(const float4*)(zbase + (size_t)sl * 384 + c4 * 4);
    tile[(c4 * 4 + 0) * 65 + sl] = v4.x;
    tile[(c4 * 4 + 1) * 65 + sl] = v4.y;
    tile[(c4 * 4 + 2) * 65 + sl] = v4.z;
    tile[(c4 * 4 + 3) * 65 + sl] = v4.w;
  }
  __syncthreads();
#pragma unroll
  for (int k = 0; k < 24; k++) {
    const int idx = tid + k * 256;       // 0..6143
    const int r  = idx >> 6;             // 0..95
    const int sl = idx & 63;
    const int fc = r >> 5;               // 0..2
    const int tl = r & 31;
    zt[((size_t)fc * T + t0 + tl) * B + s0 + sl] = tile[(tl * 3 + fc) * 65 + sl];
  }
}

// ---------------------------------------------------------------------------
// Main filter kernel (r18 structure, 48.3us measured). One wave per block;
// block b: filter f = b>>6, seq-group sblk = b&63. hist4 (p,v,P00,P01) in
// LDS t=0..126 (t=127 in regs); P11 in LDS t=0..127. z from zt[f][t][seq]
// (coalesced, register ring depth 8). Backward: LDS rings depth 2, z depth 8.
// aq: [f][T][B] float2 (a, a*e^2), valid n = 2..T-1. Fused epilogue: last
// finishing block of each seq-group reduces the group's 3 aq slices.
// ---------------------------------------------------------------------------
__global__ __launch_bounds__(CPB, 1) void filt_kernel(
    const float* __restrict__ params, const float* __restrict__ covp,
    const float* __restrict__ init_states, const float* __restrict__ zt,
    float2* __restrict__ aq, unsigned* __restrict__ cnt,
    float* __restrict__ out) {
  const int lane = threadIdx.x;            // 0..63
  const int blk  = blockIdx.x;             // 0..191
  const int f    = blk >> 6;               // filter 0=x,1=y,2=theta (uniform)
  const int sblk = blk & 63;               // seq-group
  const int seq  = (sblk << 6) + lane;

  __shared__ float4 h4s[127 * CPB];        // 130048 B, slot [t*64 + lane]
  __shared__ float  p11s[T * CPB];         //  32768 B, slot [t*64 + lane]

  // ---- shared scalars ----
  const float friction = (fast_tanh(params[0]) + 1.0f) * 0.01f;
  const float damping  = (fast_tanh(params[1]) + 1.0f) * 0.01f;
  float cp[7];
#pragma unroll
  for (int i = 0; i < 7; i++) cp[i] = sigmoidf(covp[i]);
  const float dcoef = 1.0f - DTc * damping;
  const bool isTH = (f == 2);              // wave-uniform branch
  const float q0 = isTH ? cp[5] : cp[3];
  const float q1 = isTH ? cp[6] : cp[4];
  const float r  = cp[f];

  // ---- init ----
  const int pidx = (f == 0) ? 0 : (f == 1) ? 1 : 4;
  const int vidx = (f == 0) ? 2 : (f == 1) ? 3 : 5;
  float p = init_states[seq * 6 + pidx];
  float v = init_states[seq * 6 + vidx];
  float P00 = 0.01f, P01 = 0.0f, P11 = 0.01f;

  // per-wave z stream: 64 consecutive floats per t (256 B coalesced).
  const float* __restrict__ ztf = zt + (size_t)f * T * B + seq;

  // =========================== forward ===========================
  float zr[8];
#pragma unroll
  for (int k = 0; k < 8; k++) zr[k] = ztf[(size_t)k * B];

#pragma unroll 8
  for (int t = 0; t < T; t++) {
    const float zc = zr[t & 7];
    const int tf = (t < T - 8) ? t + 8 : T - 1;      // clamped prefetch
    zr[t & 7] = ztf[(size_t)tf * B];

    float g, tv;
    if (!isTH) {
      const float th = fast_tanh(100.0f * v);
      tv = v - DTc * (damping * v + friction * th);
      g = 1.0f - DTc * (damping + 100.0f * friction * (1.0f - th * th));
    } else {
      tv = dcoef * v;
      g = dcoef;
    }
    const float tp = p + DTc * v;
    const float u = P01 + DTc * P11;
    const float Pp00 = P00 + DTc * P01 + DTc * u + q0;
    const float Pp01 = g * u;
    const float Pp11 = g * (g * P11) + q1;
    const float iS = frcp(Pp00 + r);
    const float K0 = Pp00 * iS;
    const float K1 = Pp01 * iS;
    float e = zc - tp;
    if (isTH) e = e - TWO_PIc * rintf(e * INV_2PI);  // _wrap
    p = tp + K0 * e;
    v = tv + K1 * e;
    const float om = 1.0f - K0;
    P00 = om * Pp00;
    P01 = om * Pp01;
    P11 = Pp11 - K1 * Pp01;

    if (t < 127) h4s[t * CPB + lane] = make_float4(p, v, P00, P01);
    p11s[t * CPB + lane] = P11;
  }

  // ---- terminal loss term n = T-1 (smoothed == filtered) ----
  {
    float e = ztf[(size_t)(T - 1) * B] - p;           // L2-hot
    if (isTH) {
      if (e >  PI_1_5) e -= TWO_PIc;
      if (e < -PI_1_5) e += TWO_PIc;
    }
    const float a = P00 + r;
    aq[((size_t)f * T + (T - 1)) * B + seq] = make_float2(a, a * e * e);
  }

  // =========================== backward ===========================
  // Same-wave, lane-private LDS dependence: no barrier needed.
  float sp_ = p, sv_ = v, Ps00 = P00, Ps01 = P01, Ps11 = P11;

  // LDS ring depth 2 (~300 cyc cover), z ring depth 8.
  float4 h4r[2];
  float  p11r[2];
  float  zrb[8];
  h4r[0]  = h4s[126 * CPB + lane];
  p11r[0] = p11s[126 * CPB + lane];
  h4r[1]  = h4s[125 * CPB + lane];
  p11r[1] = p11s[125 * CPB + lane];
#pragma unroll
  for (int k = 0; k < 8; k++) zrb[k] = ztf[(size_t)(126 - k) * B];

#pragma unroll 8
  for (int i = 0; i < 128; i++) {
    const int n = 126 - i;                   // 126 .. -1 (padded tail)
    const int s2 = i & 1;
    const int s8 = i & 7;
    const float4 h4 = h4r[s2];
    const float f11 = p11r[s2];
    const float zn_ = zrb[s8];
    // prefetches (clamped; padded iters read valid n=2 data)
    const int nl = (n >= 4) ? n - 2 : 2;
    h4r[s2]  = h4s[nl * CPB + lane];
    p11r[s2] = p11s[nl * CPB + lane];
    const int nz = (n >= 10) ? n - 8 : 2;
    zrb[s8] = ztf[(size_t)nz * B];

    const float fp = h4.x, fv = h4.y, f00 = h4.z, f01 = h4.w;

    float g, tv;
    if (!isTH) {
      const float th = fast_tanh(100.0f * fv);
      tv = fv - DTc * (damping * fv + friction * th);
      g = 1.0f - DTc * (damping + 100.0f * friction * (1.0f - th * th));
    } else {
      tv = dcoef * fv;
      g = dcoef;
    }
    const float tp = fp + DTc * fv;
    const float u = f01 + DTc * f11;
    const float Pp00 = f00 + DTc * f01 + DTc * u + q0;
    const float Pp01 = g * u;
    const float Pp11 = g * (g * f11) + q1;

    // G = P_f F^T Pp^{-1} (closed-form 2x2)
    const float idet = frcp(Pp00 * Pp11 - Pp01 * Pp01);
    const float W00 = f00, W01 = DTc * f00 + g * f01;
    const float W10 = f01, W11 = DTc * f01 + g * f11;
    const float G00 = (W00 * Pp11 - W01 * Pp01) * idet;
    const float G01 = (W01 * Pp00 - W00 * Pp01) * idet;
    const float G10 = (W10 * Pp11 - W11 * Pp01) * idet;
    const float G11 = (W11 * Pp00 - W10 * Pp01) * idet;

    const float ds0 = sp_ - tp, ds1 = sv_ - tv;
    const float np = fp + G00 * ds0 + G01 * ds1;
    const float nv = fv + G10 * ds0 + G11 * ds1;

    const float M00 = Ps00 - Pp00, M01 = Ps01 - Pp01, M11 = Ps11 - Pp11;
    const float GM00 = G00 * M00 + G01 * M01, GM01 = G00 * M01 + G01 * M11;
    const float GM10 = G10 * M00 + G11 * M01, GM11 = G10 * M01 + G11 * M11;
    Ps00 = f00 + GM00 * G00 + GM01 * G01;
    Ps01 = f01 + GM00 * G10 + GM01 * G11;
    Ps11 = f11 + GM10 * G10 + GM11 * G11;
    sp_ = np;
    sv_ = nv;

    if (n >= 2) {
      const float a = Ps00 + r;
      float e = zn_ - np;
      if (isTH) {
        if (e >  PI_1_5) e -= TWO_PIc;
        if (e < -PI_1_5) e += TWO_PIc;
      }
      aq[((size_t)f * T + n) * B + seq] = make_float2(a, a * e * e);
    }
  }

  // =========================== fused reduce ===========================
  // Last finishing block of the seq-group (atomicAdd returns 2) reduces the
  // group's aq slices: per (t, s): det = a_x*a_y*a_th, plus quadratic terms.
  __threadfence();
  unsigned old = 0;
  if (lane == 0) old = atomicAdd(&cnt[sblk], 1u);
  old = (unsigned)__shfl((int)old, 0);
  if (old == 2u) {
    __threadfence();  // acquire: other blocks' aq writes
    const float2* __restrict__ a0p = aq + (size_t)0 * T * B + (sblk << 6) + lane;
    const float2* __restrict__ a1p = aq + (size_t)1 * T * B + (sblk << 6) + lane;
    const float2* __restrict__ a2p = aq + (size_t)2 * T * B + (sblk << 6) + lane;
    float part = 0.0f;
#pragma unroll 4
    for (int t = 2; t < T; t++) {
      const float2 a0 = a0p[(size_t)t * B];
      const float2 a1 = a1p[(size_t)t * B];
      const float2 a2 = a2p[(size_t)t * B];
      part += a0.x * a1.x * a2.x + (a0.y + a1.y + a2.y);
    }
#pragma unroll
    for (int off = 32; off > 0; off >>= 1) part += __shfl_down(part, off);
    if (lane == 0) atomicAdd(out, part);
  }
}

}  // namespace

extern "C" void kernel_launch(void* const* d_in, const int* in_sizes, int n_in,
                              void* d_out, int out_size, void* d_ws, size_t ws_size,
                              hipStream_t stream) {
  const float* params      = (const float*)d_in[0];
  const float* covp        = (const float*)d_in[1];
  const float* init_states = (const float*)d_in[2];
  const float* z           = (const float*)d_in[3];
  float* out = (float*)d_out;

  const size_t ztB  = (size_t)T * NT * sizeof(float);    //  6.3 MB
  const size_t aqB  = (size_t)T * NT * sizeof(float2);   // 12.6 MB
  const size_t cntB = 256;
  const size_t needBytes = ztB + aqB + cntB;             // 18.9 MB

  hipMemsetAsync(d_out, 0, sizeof(float), stream);

  if (ws_size >= needBytes) {
    float*    ztp = (float*)d_ws;
    float2*   aqp = (float2*)((char*)d_ws + ztB);
    unsigned* cnt = (unsigned*)((char*)d_ws + ztB + aqB);
    ztrans_kernel<<<256, 256, 0, stream>>>(z, ztp, cnt);
    filt_kernel<<<NBLK, CPB, 0, stream>>>(params, covp, init_states, ztp,
                                          aqp, cnt, out);
  }
}

// Round 7
// 122.409 us; speedup vs baseline: 1.2511x; 1.2511x over previous
//
#include <hip/hip_runtime.h>
#include <cmath>

// Kalman_Smooth_Gradient: B=4096 seqs, T=128 steps, 6-state EKF + RTS + loss.
// Round 22: recover from r21 (fused cross-block reduce = +37us on filt via
// cross-XCD L2 reads + threadfence; reverted). Back to r18's best-measured
// filt core (48.3us) with three safe refinements:
//  1. r20's loop-splitting WITHOUT tvg4: main loops have unclamped prefetch,
//     compile-time tails fold all clamps/guards (r20 conflated this win with
//     the tvg4 regression).
//  2. Backward LDS ring depth 2 -> 4 (latency cover, same inst count).
//  3. memset dispatch removed: ztrans block 0 zeroes out. 3 dispatches.
// Model: bench = ~60us fixed + sum(kernels) + ~4us/dispatch. Wave count is
// structurally 192 (chains/64) -> wall == single-wave serial time; next
// lever if this saturates: chunked affine-scan backward (T-parallel).

namespace {

constexpr int B = 4096;
constexpr int T = 128;
constexpr int NT = B * 3;           // 12288 filter chains
constexpr int CPB = 64;             // chains (= threads) per block, one wave
constexpr int NBLK = NT / CPB;      // 192 blocks
constexpr int RBLK = 512;           // reduce kernel blocks
constexpr int RTH = 256;            // reduce kernel threads

constexpr float DTc     = 1.0f / 120.0f;
constexpr float TWO_PIc = 6.28318530717958647692f;
constexpr float PI_1_5  = 4.71238898038468985769f;
constexpr float INV_2PI = 0.15915494309189533577f;

__device__ __forceinline__ float frcp(float x) { return __builtin_amdgcn_rcpf(x); }

__device__ __forceinline__ float fast_tanh(float x) {
  float e = __expf(2.0f * x);
  return 1.0f - 2.0f * frcp(e + 1.0f);
}
__device__ __forceinline__ float sigmoidf(float x) {
  return frcp(1.0f + __expf(-x));
}

// ---------------------------------------------------------------------------
// z transpose: z[s][t][f] -> zt[f][t][s]. Block = 256 thr, tile = 64 seqs x
// 32 t x 3 f (24960 B LDS, stride-65 cols). Grid 256 blocks. Block 0 also
// zeroes the output scalar (replaces the memset dispatch; stream-ordered
// before reduce's atomics).
// ---------------------------------------------------------------------------
__global__ __launch_bounds__(256) void ztrans_kernel(
    const float* __restrict__ z, float* __restrict__ zt,
    float* __restrict__ out) {
  __shared__ float tile[96 * 65];
  const int tid = threadIdx.x;
  if (blockIdx.x == 0 && tid == 0) out[0] = 0.0f;
  const int bs = blockIdx.x & 63;        // seq-chunk 0..63
  const int bt = blockIdx.x >> 6;        // t-chunk 0..3
  const int s0 = bs * 64, t0 = bt * 32;

  const float* __restrict__ zbase = z + (size_t)s0 * 384 + t0 * 3;
#pragma unroll
  for (int k = 0; k < 6; k++) {
    const int idx = tid + k * 256;       // 0..1535
    const int sl = idx / 24;             // seq-local 0..63
    const int c4 = idx - sl * 24;        // float4 col 0..23
    const float4 v4 = *(const float4*)(zbase + (size_t)sl * 384 + c4 * 4);
    tile[(c4 * 4 + 0) * 65 + sl] = v4.x;
    tile[(c4 * 4 + 1) * 65 + sl] = v4.y;
    tile[(c4 * 4 + 2) * 65 + sl] = v4.z;
    tile[(c4 * 4 + 3) * 65 + sl] = v4.w;
  }
  __syncthreads();
#pragma unroll
  for (int k = 0; k < 24; k++) {
    const int idx = tid + k * 256;       // 0..6143
    const int r  = idx >> 6;             // 0..95
    const int sl = idx & 63;
    const int fc = r >> 5;               // 0..2
    const int tl = r & 31;
    zt[((size_t)fc * T + t0 + tl) * B + s0 + sl] = tile[(tl * 3 + fc) * 65 + sl];
  }
}

// ---------------------------------------------------------------------------
// Main filter kernel (r18 core). One wave per block; block b: filter f=b>>6,
// 64 consecutive seqs. hist4 (p,v,P00,P01) in LDS t=0..126 (t=127 in regs);
// P11 in LDS t=0..127. z from zt[f][t][seq]: coalesced 256 B loads, register
// ring depth 8. Backward: LDS rings depth 4, z ring depth 8. Loops split
// into unclamped mains + compile-time-folded tails.
// aq: [f][T][B] float2 (a, a*e^2), valid n = 2..T-1.
// ---------------------------------------------------------------------------
__global__ __launch_bounds__(CPB, 1) void filt_kernel(
    const float* __restrict__ params, const float* __restrict__ covp,
    const float* __restrict__ init_states, const float* __restrict__ zt,
    float2* __restrict__ aq) {
  const int lane = threadIdx.x;            // 0..63
  const int blk  = blockIdx.x;             // 0..191
  const int f    = blk >> 6;               // filter 0=x,1=y,2=theta (uniform)
  const int seq  = ((blk & 63) << 6) + lane;

  __shared__ float4 h4s[127 * CPB];        // 130048 B, slot [t*64 + lane]
  __shared__ float  p11s[T * CPB];         //  32768 B, slot [t*64 + lane]

  // ---- shared scalars ----
  const float friction = (fast_tanh(params[0]) + 1.0f) * 0.01f;
  const float damping  = (fast_tanh(params[1]) + 1.0f) * 0.01f;
  float cp[7];
#pragma unroll
  for (int i = 0; i < 7; i++) cp[i] = sigmoidf(covp[i]);
  const float dcoef = 1.0f - DTc * damping;
  const bool isTH = (f == 2);              // wave-uniform branch
  const float q0 = isTH ? cp[5] : cp[3];
  const float q1 = isTH ? cp[6] : cp[4];
  const float r  = cp[f];

  // ---- init ----
  const int pidx = (f == 0) ? 0 : (f == 1) ? 1 : 4;
  const int vidx = (f == 0) ? 2 : (f == 1) ? 3 : 5;
  float p = init_states[seq * 6 + pidx];
  float v = init_states[seq * 6 + vidx];
  float P00 = 0.01f, P01 = 0.0f, P11 = 0.01f;

  // per-wave z stream: 64 consecutive floats per t (256 B coalesced).
  const float* __restrict__ ztf = zt + (size_t)f * T * B + seq;

  // =========================== forward ===========================
  float zr[8];
#pragma unroll
  for (int k = 0; k < 8; k++) zr[k] = ztf[(size_t)k * B];
  float zlast = 0.0f;

#define FWD_BODY(t, REFILL)                                                  \
  {                                                                          \
    const float zc = zr[(t) & 7];                                            \
    if (REFILL) zr[(t) & 7] = ztf[(size_t)((t) + 8) * B];                    \
    float g, tv;                                                             \
    if (!isTH) {                                                             \
      const float th = fast_tanh(100.0f * v);                                \
      tv = v - DTc * (damping * v + friction * th);                          \
      g = 1.0f - DTc * (damping + 100.0f * friction * (1.0f - th * th));     \
    } else {                                                                 \
      tv = dcoef * v;                                                        \
      g = dcoef;                                                             \
    }                                                                        \
    const float tp = p + DTc * v;                                            \
    const float u = P01 + DTc * P11;                                         \
    const float Pp00 = P00 + DTc * P01 + DTc * u + q0;                       \
    const float Pp01 = g * u;                                                \
    const float Pp11 = g * (g * P11) + q1;                                   \
    const float iS = frcp(Pp00 + r);                                         \
    const float K0 = Pp00 * iS;                                              \
    const float K1 = Pp01 * iS;                                              \
    float e = zc - tp;                                                       \
    if (isTH) e = e - TWO_PIc * rintf(e * INV_2PI);                          \
    p = tp + K0 * e;                                                         \
    v = tv + K1 * e;                                                         \
    const float om = 1.0f - K0;                                              \
    P00 = om * Pp00;                                                         \
    P01 = om * Pp01;                                                         \
    P11 = Pp11 - K1 * Pp01;                                                  \
    if ((t) < 127) h4s[(t) * CPB + lane] = make_float4(p, v, P00, P01);      \
    p11s[(t) * CPB + lane] = P11;                                            \
    if ((t) == 127) zlast = zc;                                              \
  }

#pragma unroll 8
  for (int t = 0; t < 120; t++) FWD_BODY(t, true)
#pragma unroll
  for (int t = 120; t < 128; t++) FWD_BODY(t, false)
#undef FWD_BODY

  // ---- terminal loss term n = T-1 (smoothed == filtered) ----
  {
    float e = zlast - p;
    if (isTH) {
      if (e >  PI_1_5) e -= TWO_PIc;
      if (e < -PI_1_5) e += TWO_PIc;
    }
    const float a = P00 + r;
    aq[((size_t)f * T + (T - 1)) * B + seq] = make_float2(a, a * e * e);
  }

  // =========================== backward ===========================
  // Same-wave, lane-private LDS dependence: no barrier needed.
  float sp_ = p, sv_ = v, Ps00 = P00, Ps01 = P01, Ps11 = P11;

  // Rings: h4/p11 LDS depth 4, z depth 8.
  float4 h4r[4];
  float  p11r[4];
  float  zrb[8];
#pragma unroll
  for (int k = 0; k < 4; k++) {
    h4r[k]  = h4s[(126 - k) * CPB + lane];
    p11r[k] = p11s[(126 - k) * CPB + lane];
  }
#pragma unroll
  for (int k = 0; k < 8; k++) zrb[k] = ztf[(size_t)(126 - k) * B];

#define BWD_BODY(i, RH4, RZ)                                                 \
  {                                                                          \
    const int n = 126 - (i);                                                 \
    const float4 h4 = h4r[(i) & 3];                                          \
    const float f11 = p11r[(i) & 3];                                         \
    const float zn_ = zrb[(i) & 7];                                          \
    if (RH4) {                                                               \
      h4r[(i) & 3]  = h4s[(n - 4) * CPB + lane];                             \
      p11r[(i) & 3] = p11s[(n - 4) * CPB + lane];                            \
    }                                                                        \
    if (RZ) zrb[(i) & 7] = ztf[(size_t)(n - 8) * B];                         \
    const float fp = h4.x, fv = h4.y, f00 = h4.z, f01 = h4.w;                \
    float g, tv;                                                             \
    if (!isTH) {                                                             \
      const float th = fast_tanh(100.0f * fv);                               \
      tv = fv - DTc * (damping * fv + friction * th);                        \
      g = 1.0f - DTc * (damping + 100.0f * friction * (1.0f - th * th));     \
    } else {                                                                 \
      tv = dcoef * fv;                                                       \
      g = dcoef;                                                             \
    }                                                                        \
    const float tp = fp + DTc * fv;                                          \
    const float u = f01 + DTc * f11;                                         \
    const float Pp00 = f00 + DTc * f01 + DTc * u + q0;                       \
    const float Pp01 = g * u;                                                \
    const float Pp11 = g * (g * f11) + q1;                                   \
    const float idet = frcp(Pp00 * Pp11 - Pp01 * Pp01);                      \
    const float W00 = f00, W01 = DTc * f00 + g * f01;                        \
    const float W10 = f01, W11 = DTc * f01 + g * f11;                        \
    const float G00 = (W00 * Pp11 - W01 * Pp01) * idet;                      \
    const float G01 = (W01 * Pp00 - W00 * Pp01) * idet;                      \
    const float G10 = (W10 * Pp11 - W11 * Pp01) * idet;                      \
    const float G11 = (W11 * Pp00 - W10 * Pp01) * idet;                      \
    const float ds0 = sp_ - tp, ds1 = sv_ - tv;                              \
    const float np = fp + G00 * ds0 + G01 * ds1;                             \
    const float nv = fv + G10 * ds0 + G11 * ds1;                             \
    const float M00 = Ps00 - Pp00, M01 = Ps01 - Pp01, M11 = Ps11 - Pp11;     \
    const float GM00 = G00 * M00 + G01 * M01, GM01 = G00 * M01 + G01 * M11;  \
    const float GM10 = G10 * M00 + G11 * M01, GM11 = G10 * M01 + G11 * M11;  \
    Ps00 = f00 + GM00 * G00 + GM01 * G01;                                    \
    Ps01 = f01 + GM00 * G10 + GM01 * G11;                                    \
    Ps11 = f11 + GM10 * G10 + GM11 * G11;                                    \
    sp_ = np;                                                                \
    sv_ = nv;                                                                \
    const float a = Ps00 + r;                                                \
    float e = zn_ - np;                                                      \
    if (isTH) {                                                              \
      if (e >  PI_1_5) e -= TWO_PIc;                                         \
      if (e < -PI_1_5) e += TWO_PIc;                                         \
    }                                                                        \
    aq[((size_t)f * T + n) * B + seq] = make_float2(a, a * e * e);           \
  }

  // main: i = 0..111 (n = 126..15): refill targets n-4 >= 11, n-8 >= 7, both
  // valid unclamped. tail: i = 112..124 (n = 14..2): full unroll; refill
  // guards (future consumer exists) fold at compile time.
#pragma unroll 8
  for (int i = 0; i < 112; i++) BWD_BODY(i, true, true)
#pragma unroll
  for (int i = 112; i < 125; i++)
    BWD_BODY(i, (126 - i) >= 6, (126 - i) >= 10)
#undef BWD_BODY
}

// ---------------------------------------------------------------------------
// Reduce kernel: per (t, seq), det term = a_x*a_y*a_th (Sv diagonal) plus
// quadratic terms. float4 loads = two (t,s) terms per load per stream.
// ---------------------------------------------------------------------------
__global__ __launch_bounds__(RTH) void reduce_kernel(
    const float4* __restrict__ aq4, float* __restrict__ out) {
  const int tid = threadIdx.x;
  constexpr int HB = B / 2;            // 2048 float4 per (f,t) row
  constexpr int NTERM4 = 126 * HB;     // t = 2..127
  float part = 0.0f;
  for (int idx = blockIdx.x * RTH + tid; idx < NTERM4; idx += RTH * RBLK) {
    const int t = 2 + (idx >> 11);     // / 2048
    const int s4 = idx & (HB - 1);
    const float4 a0 = aq4[((size_t)0 * T + t) * HB + s4];
    const float4 a1 = aq4[((size_t)1 * T + t) * HB + s4];
    const float4 a2 = aq4[((size_t)2 * T + t) * HB + s4];
    part += a0.x * a1.x * a2.x + (a0.y + a1.y + a2.y);
    part += a0.z * a1.z * a2.z + (a0.w + a1.w + a2.w);
  }
  // wave reduce + cross-wave via LDS + one atomic per block
#pragma unroll
  for (int off = 32; off > 0; off >>= 1) part += __shfl_down(part, off);
  __shared__ float red[RTH / 64];
  if ((tid & 63) == 0) red[tid >> 6] = part;
  __syncthreads();
  if (tid == 0) {
    float s = 0.0f;
#pragma unroll
    for (int w = 0; w < RTH / 64; w++) s += red[w];
    atomicAdd(out, s);
  }
}

}  // namespace

extern "C" void kernel_launch(void* const* d_in, const int* in_sizes, int n_in,
                              void* d_out, int out_size, void* d_ws, size_t ws_size,
                              hipStream_t stream) {
  const float* params      = (const float*)d_in[0];
  const float* covp        = (const float*)d_in[1];
  const float* init_states = (const float*)d_in[2];
  const float* z           = (const float*)d_in[3];
  float* out = (float*)d_out;

  const size_t ztB = (size_t)T * NT * sizeof(float);    //  6.3 MB
  const size_t aqB = (size_t)T * NT * sizeof(float2);   // 12.6 MB
  const size_t needBytes = ztB + aqB;                   // 18.9 MB

  if (ws_size >= needBytes) {
    float*  ztp = (float*)d_ws;
    float2* aqp = (float2*)((char*)d_ws + ztB);
    ztrans_kernel<<<256, 256, 0, stream>>>(z, ztp, out);
    filt_kernel<<<NBLK, CPB, 0, stream>>>(params, covp, init_states, ztp, aqp);
    reduce_kernel<<<RBLK, RTH, 0, stream>>>((const float4*)aqp, out);
  } else {
    hipMemsetAsync(d_out, 0, sizeof(float), stream);
  }
}